// Round 1
// baseline (238.733 us; speedup 1.0000x reference)
//
#include <hip/hip_runtime.h>
#include <math.h>

#define NC 512
#define NB 2
#define M 1024
#define KS 24
#define NA 60
#define CO 128
#define CELLS 1440      // NA*KS
#define CELLS_PAD 1536
#define NTOT 30720.0f   // NC*NA
// log2(e)/SIGMA, SIGMA=0.08
#define LSCALE 18.033688011112043f

// feat geometry in d_out
#define FEAT_OFF 3072
#define FEAT_N 7864320
#define ANCH_OFF (3072 + 7864320)

// ---------------- K0: per-cell constants (kx,ky,kz)*2L, -k2*L ----------------
__global__ void k_setup(const float* __restrict__ kernels, float4* __restrict__ kc) {
    int cell = blockIdx.x * blockDim.x + threadIdx.x;
    if (cell >= CELLS_PAD) return;
    int a = cell / KS, k = cell % KS;
    float4 v;
    if (a < NA) {
        float kx = kernels[(k * NA + a) * 3 + 0];
        float ky = kernels[(k * NA + a) * 3 + 1];
        float kz = kernels[(k * NA + a) * 3 + 2];
        float k2 = kx * kx + ky * ky + kz * kz;
        v = make_float4(kx * (2.0f * LSCALE), ky * (2.0f * LSCALE),
                        kz * (2.0f * LSCALE), -k2 * LSCALE);
    } else {
        v = make_float4(0.f, 0.f, 0.f, -1e30f);  // exp2 -> 0
    }
    kc[cell] = v;
}

// ---------------- K1: wts[b,n,cell] = sum_m masked exp2(...) / (cnt+1) -------
__launch_bounds__(256)
__global__ void k_wts(const float* __restrict__ frag, const float* __restrict__ clouds,
                      const float4* __restrict__ kc, float* __restrict__ wts) {
    int bn = blockIdx.x;
    int b = bn >> 9, n = bn & (NC - 1);
    int tid = threadIdx.x;
    __shared__ float sdx[M], sdy[M], sdz[M], sd2[M];
    __shared__ int scnt;
    if (tid == 0) scnt = 0;
    __syncthreads();
    float cx = clouds[b * 3 * NC + n];
    float cy = clouds[b * 3 * NC + NC + n];
    float cz = clouds[b * 3 * NC + 2 * NC + n];
    for (int j = 0; j < 4; ++j) {
        int m = tid + j * 256;
        float dx = frag[3 * m]     - cx;
        float dy = frag[3 * m + 1] - cy;
        float dz = frag[3 * m + 2] - cz;
        // match jnp's non-contracted sum of squares (mask boundary exactness)
        float s = __fmul_rn(dx, dx);
        s = __fadd_rn(s, __fmul_rn(dy, dy));
        s = __fadd_rn(s, __fmul_rn(dz, dz));
        if (s < 0.16f) {  // f32(RADIUS*RADIUS)
            int p = atomicAdd(&scnt, 1);
            sdx[p] = dx; sdy[p] = dy; sdz[p] = dz;
            sd2[p] = s * LSCALE;
        }
    }
    __syncthreads();
    int cnt = scnt;

    float4 kcr[6];
    #pragma unroll
    for (int j = 0; j < 6; ++j) kcr[j] = kc[tid + j * 256];
    float acc[6] = {0.f, 0.f, 0.f, 0.f, 0.f, 0.f};

    for (int i = 0; i < cnt; ++i) {
        float dx = sdx[i], dy = sdy[i], dz = sdz[i];  // LDS broadcast reads
        float Ei = exp2f(-sd2[i]);
        #pragma unroll
        for (int j = 0; j < 6; ++j) {
            float arg = fmaf(dx, kcr[j].x,
                        fmaf(dy, kcr[j].y,
                        fmaf(dz, kcr[j].z, kcr[j].w)));
            acc[j] = fmaf(exp2f(arg), Ei, acc[j]);
        }
    }

    float inv = 1.0f / (float)(cnt + 1);
    float* wrow = wts + (size_t)bn * CELLS;
    #pragma unroll
    for (int j = 0; j < 6; ++j) {
        int cell = tid + j * 256;
        if (cell < CELLS) wrow[cell] = acc[j] * inv;
    }
}

// ---------------- K2: per-(b,c) sum & sumsq of feats via recompute -----------
__launch_bounds__(256)
__global__ void k_stats(const float* __restrict__ wts, const float* __restrict__ W,
                        float* __restrict__ acc) {
    int bn = blockIdx.x;
    int b = bn >> 9;
    int tid = threadIdx.x;
    __shared__ float wl[CELLS];
    for (int j = 0; j < 6; ++j) {
        int cell = tid + j * 256;
        if (cell < CELLS) wl[cell] = wts[(size_t)bn * CELLS + cell];
    }
    __syncthreads();
    int c = tid >> 1, half = tid & 1;
    float wr[KS];
    #pragma unroll
    for (int k = 0; k < KS; ++k) wr[k] = W[c * KS + k];
    float s = 0.f, s2 = 0.f;
    int a0 = half * 30;
    for (int a = a0; a < a0 + 30; ++a) {
        const float* vp = wl + a * KS;
        float f = 0.f;
        #pragma unroll
        for (int k = 0; k < KS; ++k) f = fmaf(wr[k], vp[k], f);
        s += f;
        s2 = fmaf(f, f, s2);
    }
    s  += __shfl_xor(s, 1);
    s2 += __shfl_xor(s2, 1);
    if (half == 0) {
        atomicAdd(&acc[(b * CO + c) * 2 + 0], s);
        atomicAdd(&acc[(b * CO + c) * 2 + 1], s2);
    }
}

// ---------------- K2b: mu, rsqrt(var+eps) per (b,c) --------------------------
__global__ void k_finalize_stats(const float* __restrict__ acc, float* __restrict__ stats) {
    int i = threadIdx.x;  // 0..255 == b*CO + c
    float s = acc[i * 2], s2 = acc[i * 2 + 1];
    const float invN = 1.0f / NTOT;
    float mu = s * invN;
    float var = fmaf(-mu, mu, s2 * invN);
    var = fmaxf(var, 0.f);
    float rs = rsqrtf(var + 1e-5f);
    stats[i * 2] = mu;
    stats[i * 2 + 1] = rs;
}

// ---------------- K3: feat = relu((W@wts - mu)*rs) ---------------------------
__launch_bounds__(256)
__global__ void k_out(const float* __restrict__ wts, const float* __restrict__ W,
                      const float* __restrict__ stats, float* __restrict__ out) {
    int bn = blockIdx.x;
    int b = bn >> 9, n = bn & (NC - 1);
    int tid = threadIdx.x;
    __shared__ float wl[CELLS];
    for (int j = 0; j < 6; ++j) {
        int cell = tid + j * 256;
        if (cell < CELLS) wl[cell] = wts[(size_t)bn * CELLS + cell];
    }
    __syncthreads();
    int c = tid >> 1, half = tid & 1;
    float wr[KS];
    #pragma unroll
    for (int k = 0; k < KS; ++k) wr[k] = W[c * KS + k];
    float mu = stats[(b * CO + c) * 2], rs = stats[(b * CO + c) * 2 + 1];
    float* orow = out + FEAT_OFF + ((size_t)(b * CO + c) * NC + n) * NA;
    int a0 = half * 30;
    for (int a = a0; a < a0 + 30; ++a) {
        const float* vp = wl + a * KS;
        float f = 0.f;
        #pragma unroll
        for (int k = 0; k < KS; ++k) f = fmaf(wr[k], vp[k], f);
        float val = (f - mu) * rs;
        orow[a] = fmaxf(val, 0.f);
    }
}

extern "C" void kernel_launch(void* const* d_in, const int* in_sizes, int n_in,
                              void* d_out, int out_size, void* d_ws, size_t ws_size,
                              hipStream_t stream) {
    const float* frag    = (const float*)d_in[0];
    const float* clouds  = (const float*)d_in[1];
    const float* kernels = (const float*)d_in[2];
    const float* W       = (const float*)d_in[3];
    const float* anchors = (const float*)d_in[4];
    float* out = (float*)d_out;

    char* ws = (char*)d_ws;
    float*  wts   = (float*)(ws);                         // 1024*1440*4 = 5,898,240 B
    float4* kc    = (float4*)(ws + 5898240);              // 1536*16    = 24,576 B
    float*  acc   = (float*)(ws + 5898240 + 24576);       // 512*4      = 2,048 B
    float*  stats = (float*)(ws + 5898240 + 24576 + 2048);// 512*4

    // passthrough outputs
    hipMemcpyAsync(out, clouds, 3072 * sizeof(float), hipMemcpyDeviceToDevice, stream);
    hipMemcpyAsync(out + ANCH_OFF, anchors, 540 * sizeof(float), hipMemcpyDeviceToDevice, stream);
    hipMemsetAsync(acc, 0, 2048, stream);

    k_setup<<<6, 256, 0, stream>>>(kernels, kc);
    k_wts<<<NB * NC, 256, 0, stream>>>(frag, clouds, kc, wts);
    k_stats<<<NB * NC, 256, 0, stream>>>(wts, W, acc);
    k_finalize_stats<<<1, 256, 0, stream>>>(acc, stats);
    k_out<<<NB * NC, 256, 0, stream>>>(wts, W, stats, out);
}

// Round 2
// 208.318 us; speedup vs baseline: 1.1460x; 1.1460x over previous
//
#include <hip/hip_runtime.h>
#include <math.h>

#define NC 512
#define NB 2
#define M 1024
#define KS 24
#define NA 60
#define CO 128
#define CELLS 1440
#define NTOT 30720.0f
// log2(e)/SIGMA, SIGMA=0.08
#define LSCALE 18.033688011112043f
#define R2 0.16f

#define FEAT_OFF 3072
#define ANCH_OFF (3072 + 7864320)

__device__ __forceinline__ float dot4acc(float s, float4 w, float4 v) {
    return fmaf(w.x, v.x, fmaf(w.y, v.y, fmaf(w.z, v.z, fmaf(w.w, v.w, s))));
}

// ---------- K1: wts[bn][cell] = sum_m masked exp2(...) / (cnt+1) ----------
// grid 3072: 3 chunks of 512 cells per bn; 2 cells/thread.
__launch_bounds__(256)
__global__ void k_wts(const float* __restrict__ frag, const float* __restrict__ clouds,
                      const float* __restrict__ kernels, float* __restrict__ wts) {
    int bx = blockIdx.x;
    int chunk = bx % 3;
    int bn = bx / 3;
    int b = bn >> 9, n = bn & (NC - 1);
    int tid = threadIdx.x, wave = tid >> 6, lane = tid & 63;
    __shared__ float4 spl[M];
    __shared__ int wcnt[16];

    // per-thread cell constants (folded k_setup)
    int c0 = chunk * 512;
    float4 kc0, kc1;
    {
        int cells[2] = {c0 + tid, c0 + 256 + tid};
        float4* kcs[2] = {&kc0, &kc1};
        #pragma unroll
        for (int q = 0; q < 2; ++q) {
            int cell = cells[q];
            if (cell < CELLS) {
                int a = cell / KS, k = cell - a * KS;
                const float* kp = kernels + (size_t)(k * NA + a) * 3;
                float kx = kp[0], ky = kp[1], kz = kp[2];
                float k2 = kx * kx + ky * ky + kz * kz;
                *kcs[q] = make_float4(kx * (2.0f * LSCALE), ky * (2.0f * LSCALE),
                                      kz * (2.0f * LSCALE), -k2 * LSCALE);
            } else {
                *kcs[q] = make_float4(0.f, 0.f, 0.f, -1e30f);  // exp2 -> 0
            }
        }
    }

    float cx = clouds[b * 3 * NC + n];
    float cy = clouds[b * 3 * NC + NC + n];
    float cz = clouds[b * 3 * NC + 2 * NC + n];

    float dx[4], dy[4], dz[4], ei[4];
    int pos[4];
    bool pr[4];
    unsigned long long lmask = (1ull << lane) - 1ull;
    #pragma unroll
    for (int j = 0; j < 4; ++j) {
        int m = tid + j * 256;
        dx[j] = frag[3 * m]     - cx;
        dy[j] = frag[3 * m + 1] - cy;
        dz[j] = frag[3 * m + 2] - cz;
        // match jnp's non-contracted sum of squares (mask boundary exactness)
        float s = __fmul_rn(dx[j], dx[j]);
        s = __fadd_rn(s, __fmul_rn(dy[j], dy[j]));
        s = __fadd_rn(s, __fmul_rn(dz[j], dz[j]));
        pr[j] = s < R2;
        ei[j] = exp2f(-s * LSCALE);
        unsigned long long mk = __ballot(pr[j]);
        pos[j] = __popcll(mk & lmask);
        if (lane == 0) wcnt[j * 4 + wave] = __popcll(mk);
    }
    __syncthreads();
    int run = 0, base[4];
    #pragma unroll
    for (int t2 = 0; t2 < 16; ++t2) {
        if ((t2 & 3) == wave) base[t2 >> 2] = run;
        run += wcnt[t2];
    }
    int cnt = run;
    #pragma unroll
    for (int j = 0; j < 4; ++j)
        if (pr[j]) spl[base[j] + pos[j]] = make_float4(dx[j], dy[j], dz[j], ei[j]);
    __syncthreads();

    float acc0 = 0.f, acc1 = 0.f;
    #pragma unroll 2
    for (int i = 0; i < cnt; ++i) {
        float4 p = spl[i];  // ds_read_b128 broadcast; p.w = exp2(-d2*L)
        float a0 = fmaf(p.x, kc0.x, fmaf(p.y, kc0.y, fmaf(p.z, kc0.z, kc0.w)));
        float a1 = fmaf(p.x, kc1.x, fmaf(p.y, kc1.y, fmaf(p.z, kc1.z, kc1.w)));
        acc0 = fmaf(exp2f(a0), p.w, acc0);
        acc1 = fmaf(exp2f(a1), p.w, acc1);
    }

    float inv = 1.0f / (float)(cnt + 1);
    float* wrow = wts + (size_t)bn * CELLS;
    int cell0 = c0 + tid, cell1 = c0 + 256 + tid;
    if (cell0 < CELLS) wrow[cell0] = acc0 * inv;
    if (cell1 < CELLS) wrow[cell1] = acc1 * inv;
}

// ---------- K2: Gram matrix G[b][24][24] + sk[b][24] over (n,a) ----------
// grid 256 blocks x 4 bn each. Gbuf layout: [b][608]: 576 G + 24 sk.
__launch_bounds__(256)
__global__ void k_gram(const float* __restrict__ wts, float* __restrict__ Gbuf) {
    int tid = threadIdx.x;
    int b = blockIdx.x >> 7;
    __shared__ float wl[CELLS];
    int e0 = tid, e1 = tid + 256, e2 = tid + 512;
    int j0 = e0 / KS, k0 = e0 % KS;
    int j1 = e1 / KS, k1 = e1 % KS;
    int j2 = e2 / KS, k2e = e2 % KS;
    float g0 = 0.f, g1 = 0.f, g2 = 0.f, sk = 0.f;
    for (int q = 0; q < 4; ++q) {
        int bn = blockIdx.x * 4 + q;
        __syncthreads();
        const float4* src = (const float4*)(wts + (size_t)bn * CELLS);
        float4* wl4 = (float4*)wl;
        wl4[tid] = src[tid];
        if (tid < 104) wl4[tid + 256] = src[tid + 256];
        __syncthreads();
        for (int a = 0; a < NA; ++a) {
            const float* v = wl + a * KS;
            g0 = fmaf(v[j0], v[k0], g0);
            g1 = fmaf(v[j1], v[k1], g1);
            if (e2 < 576) g2 = fmaf(v[j2], v[k2e], g2);
            if (tid < KS) sk += v[tid];
        }
    }
    float* Gb = Gbuf + b * 608;
    atomicAdd(&Gb[e0], g0);
    atomicAdd(&Gb[e1], g1);
    if (e2 < 576) atomicAdd(&Gb[e2], g2);
    if (tid < KS) atomicAdd(&Gb[576 + tid], sk);
}

// ---------- K2b: mu, rsqrt(var+eps) per (b,c) ----------
__global__ void k_finalize(const float* __restrict__ Gbuf, const float* __restrict__ W,
                           float* __restrict__ stats) {
    int t = threadIdx.x;  // 0..255 = b*128 + c
    int b = t >> 7, c = t & 127;
    const float* G = Gbuf + b * 608;
    const float* sk = G + 576;
    float wr[KS];
    #pragma unroll
    for (int k = 0; k < KS; ++k) wr[k] = W[c * KS + k];
    float s = 0.f;
    #pragma unroll
    for (int k = 0; k < KS; ++k) s = fmaf(wr[k], sk[k], s);
    float s2 = 0.f;
    for (int j = 0; j < KS; ++j) {
        float in = 0.f;
        #pragma unroll
        for (int k = 0; k < KS; ++k) in = fmaf(G[j * KS + k], wr[k], in);
        s2 = fmaf(wr[j], in, s2);
    }
    const float invN = 1.0f / NTOT;
    float mu = s * invN;
    float var = fmaxf(fmaf(-mu, mu, s2 * invN), 0.f);
    float rs = rsqrtf(var + 1e-5f);
    stats[t * 2] = mu;
    stats[t * 2 + 1] = rs;
}

// ---------- K3: feat = relu((W@wts - mu)*rs), coalesced row stores ----------
__launch_bounds__(256)
__global__ void k_out(const float* __restrict__ wts, const float* __restrict__ W,
                      const float* __restrict__ stats, float* __restrict__ out) {
    int bn = blockIdx.x, b = bn >> 9, n = bn & (NC - 1);
    int tid = threadIdx.x, wave = tid >> 6, lane = tid & 63;
    __shared__ float wl[CELLS];
    __shared__ float fl[32 * 60];
    {
        const float4* src = (const float4*)(wts + (size_t)bn * CELLS);
        float4* wl4 = (float4*)wl;
        wl4[tid] = src[tid];
        if (tid < 104) wl4[tid + 256] = src[tid + 256];
    }
    __syncthreads();

    // 2 c x 15 a register tile per thread
    int cpair = tid >> 2, aq = tid & 3;
    int c0 = cpair * 2, a0 = aq * 15;
    float4 w0[6], w1[6];
    {
        const float4* W40 = (const float4*)(W + c0 * KS);
        const float4* W41 = (const float4*)(W + (c0 + 1) * KS);
        #pragma unroll
        for (int j = 0; j < 6; ++j) { w0[j] = W40[j]; w1[j] = W41[j]; }
    }
    float mu0 = stats[(b * CO + c0) * 2],     rs0 = stats[(b * CO + c0) * 2 + 1];
    float mu1 = stats[(b * CO + c0 + 1) * 2], rs1 = stats[(b * CO + c0 + 1) * 2 + 1];
    float f0[15], f1[15];
    #pragma unroll
    for (int i = 0; i < 15; ++i) {
        const float4* v4 = (const float4*)(wl + (a0 + i) * KS);
        float s0 = 0.f, s1 = 0.f;
        #pragma unroll
        for (int j = 0; j < 6; ++j) {
            float4 v = v4[j];
            s0 = dot4acc(s0, w0[j], v);
            s1 = dot4acc(s1, w1[j], v);
        }
        f0[i] = fmaxf((s0 - mu0) * rs0, 0.f);
        f1[i] = fmaxf((s1 - mu1) * rs1, 0.f);
    }

    // transpose through LDS in 4 c-groups of 32, store 240B rows wave-wide
    for (int cg = 0; cg < 4; ++cg) {
        __syncthreads();
        if (wave == cg) {
            int cl = c0 & 31;
            #pragma unroll
            for (int i = 0; i < 15; ++i) {
                fl[cl * 60 + a0 + i]       = f0[i];
                fl[(cl + 1) * 60 + a0 + i] = f1[i];
            }
        }
        __syncthreads();
        #pragma unroll
        for (int i = 0; i < 8; ++i) {
            int cl = wave * 8 + i;
            int cc = cg * 32 + cl;
            if (lane < NA)
                out[FEAT_OFF + (((size_t)(b * CO + cc)) * NC + n) * NA + lane] = fl[cl * 60 + lane];
        }
    }
}

extern "C" void kernel_launch(void* const* d_in, const int* in_sizes, int n_in,
                              void* d_out, int out_size, void* d_ws, size_t ws_size,
                              hipStream_t stream) {
    const float* frag    = (const float*)d_in[0];
    const float* clouds  = (const float*)d_in[1];
    const float* kernels = (const float*)d_in[2];
    const float* W       = (const float*)d_in[3];
    const float* anchors = (const float*)d_in[4];
    float* out = (float*)d_out;

    char* ws = (char*)d_ws;
    float* wts   = (float*)(ws);                       // 1024*1440*4 = 5,898,240 B
    float* Gbuf  = (float*)(ws + 5898240);             // 2*608*4    = 4,864 B
    float* stats = (float*)(ws + 5898240 + 4864);      // 256*2*4    = 2,048 B

    hipMemcpyAsync(out, clouds, 3072 * sizeof(float), hipMemcpyDeviceToDevice, stream);
    hipMemcpyAsync(out + ANCH_OFF, anchors, 540 * sizeof(float), hipMemcpyDeviceToDevice, stream);
    hipMemsetAsync(Gbuf, 0, 2 * 608 * sizeof(float), stream);

    k_wts<<<3 * NB * NC, 256, 0, stream>>>(frag, clouds, kernels, wts);
    k_gram<<<256, 256, 0, stream>>>(wts, Gbuf);
    k_finalize<<<1, 256, 0, stream>>>(Gbuf, W, stats);
    k_out<<<NB * NC, 256, 0, stream>>>(wts, W, stats, out);
}

// Round 3
// 161.545 us; speedup vs baseline: 1.4778x; 1.2895x over previous
//
#include <hip/hip_runtime.h>
#include <math.h>

#define NC 512
#define NB 2
#define M 1024
#define KS 24
#define NA 60
#define CO 128
#define CELLS 1440
#define NTOT 30720.0f
// log2(e)/SIGMA, SIGMA=0.08
#define LSCALE 18.033688011112043f
#define R2 0.16f

#define FEAT_OFF 3072
#define ANCH_OFF (3072 + 7864320)
#define NSLOT 8

__device__ __forceinline__ float dot4acc(float s, float4 w, float4 v) {
    return fmaf(w.x, v.x, fmaf(w.y, v.y, fmaf(w.z, v.z, fmaf(w.w, v.w, s))));
}

// ---------- K1: wts[bn][cell] = sum_m masked exp2(...) / (cnt+1) ----------
// grid 3072: 3 chunks of 512 cells per bn; 2 cells/thread.
__launch_bounds__(256)
__global__ void k_wts(const float* __restrict__ frag, const float* __restrict__ clouds,
                      const float* __restrict__ kernels, float* __restrict__ wts) {
    int bx = blockIdx.x;
    int chunk = bx % 3;
    int bn = bx / 3;
    int b = bn >> 9, n = bn & (NC - 1);
    int tid = threadIdx.x, wave = tid >> 6, lane = tid & 63;
    __shared__ float4 spl[M];
    __shared__ int wcnt[16];

    // per-thread cell constants
    int c0 = chunk * 512;
    float4 kc0, kc1;
    {
        int cells[2] = {c0 + tid, c0 + 256 + tid};
        float4* kcs[2] = {&kc0, &kc1};
        #pragma unroll
        for (int q = 0; q < 2; ++q) {
            int cell = cells[q];
            if (cell < CELLS) {
                int a = cell / KS, k = cell - a * KS;
                const float* kp = kernels + (size_t)(k * NA + a) * 3;
                float kx = kp[0], ky = kp[1], kz = kp[2];
                float k2 = kx * kx + ky * ky + kz * kz;
                *kcs[q] = make_float4(kx * (2.0f * LSCALE), ky * (2.0f * LSCALE),
                                      kz * (2.0f * LSCALE), -k2 * LSCALE);
            } else {
                *kcs[q] = make_float4(0.f, 0.f, 0.f, -1e30f);  // hw exp2 -> 0
            }
        }
    }

    float cx = clouds[b * 3 * NC + n];
    float cy = clouds[b * 3 * NC + NC + n];
    float cz = clouds[b * 3 * NC + 2 * NC + n];

    float dx[4], dy[4], dz[4], ei[4];
    int pos[4];
    bool pr[4];
    unsigned long long lmask = (1ull << lane) - 1ull;
    #pragma unroll
    for (int j = 0; j < 4; ++j) {
        int m = tid + j * 256;
        dx[j] = frag[3 * m]     - cx;
        dy[j] = frag[3 * m + 1] - cy;
        dz[j] = frag[3 * m + 2] - cz;
        // match jnp's non-contracted sum of squares (mask boundary exactness)
        float s = __fmul_rn(dx[j], dx[j]);
        s = __fadd_rn(s, __fmul_rn(dy[j], dy[j]));
        s = __fadd_rn(s, __fmul_rn(dz[j], dz[j]));
        pr[j] = s < R2;
        ei[j] = __builtin_amdgcn_exp2f(-s * LSCALE);
        unsigned long long mk = __ballot(pr[j]);
        pos[j] = __popcll(mk & lmask);
        if (lane == 0) wcnt[j * 4 + wave] = __popcll(mk);
    }
    __syncthreads();
    int run = 0, base[4];
    #pragma unroll
    for (int t2 = 0; t2 < 16; ++t2) {
        if ((t2 & 3) == wave) base[t2 >> 2] = run;
        run += wcnt[t2];
    }
    int cnt = run;
    #pragma unroll
    for (int j = 0; j < 4; ++j)
        if (pr[j]) spl[base[j] + pos[j]] = make_float4(dx[j], dy[j], dz[j], ei[j]);
    __syncthreads();

    float acc0 = 0.f, acc1 = 0.f;
    #pragma unroll 2
    for (int i = 0; i < cnt; ++i) {
        float4 p = spl[i];  // ds_read_b128 broadcast; p.w = exp2(-d2*L)
        float a0 = fmaf(p.x, kc0.x, fmaf(p.y, kc0.y, fmaf(p.z, kc0.z, kc0.w)));
        float a1 = fmaf(p.x, kc1.x, fmaf(p.y, kc1.y, fmaf(p.z, kc1.z, kc1.w)));
        acc0 = fmaf(__builtin_amdgcn_exp2f(a0), p.w, acc0);
        acc1 = fmaf(__builtin_amdgcn_exp2f(a1), p.w, acc1);
    }

    float inv = 1.0f / (float)(cnt + 1);
    float* wrow = wts + (size_t)bn * CELLS;
    int cell0 = c0 + tid, cell1 = c0 + 256 + tid;
    if (cell0 < CELLS) wrow[cell0] = acc0 * inv;
    if (cell1 < CELLS) wrow[cell1] = acc1 * inv;
}

// ---------- K2: Gram G[b][24][24] + sk[b][24], 1 bn per block ----------
// Gbuf layout: [b][slot][608] (576 G + 24 sk + 8 pad)
__launch_bounds__(256)
__global__ void k_gram(const float* __restrict__ wts, float* __restrict__ Gbuf) {
    int bn = blockIdx.x;
    int b = bn >> 9;
    int slot = (bn >> 1) & (NSLOT - 1);
    int tid = threadIdx.x;
    __shared__ float wl[CELLS];
    {
        const float4* src = (const float4*)(wts + (size_t)bn * CELLS);
        float4* wl4 = (float4*)wl;
        wl4[tid] = src[tid];
        if (tid < 104) wl4[tid + 256] = src[tid + 256];
    }
    __syncthreads();

    float* Gb = Gbuf + (b * NSLOT + slot) * 608;
    if (tid < 144) {
        int j = tid / 6, kq = tid % 6;
        float g0 = 0.f, g1 = 0.f, g2 = 0.f, g3 = 0.f;
        for (int a = 0; a < NA; ++a) {
            float vj = wl[a * KS + j];
            const float4 v = *(const float4*)(wl + a * KS + kq * 4);
            g0 = fmaf(vj, v.x, g0);
            g1 = fmaf(vj, v.y, g1);
            g2 = fmaf(vj, v.z, g2);
            g3 = fmaf(vj, v.w, g3);
        }
        atomicAdd(&Gb[j * KS + kq * 4 + 0], g0);
        atomicAdd(&Gb[j * KS + kq * 4 + 1], g1);
        atomicAdd(&Gb[j * KS + kq * 4 + 2], g2);
        atomicAdd(&Gb[j * KS + kq * 4 + 3], g3);
    } else if (tid < 144 + KS) {
        int k = tid - 144;
        float sk = 0.f;
        for (int a = 0; a < NA; ++a) sk += wl[a * KS + k];
        atomicAdd(&Gb[576 + k], sk);
    }
}

// ---------- K2b: stats per (b,c) + passthrough copies ----------
__launch_bounds__(256)
__global__ void k_finalize(const float* __restrict__ Gbuf, const float* __restrict__ W,
                           const float* __restrict__ clouds, const float* __restrict__ anchors,
                           float* __restrict__ stats, float* __restrict__ out) {
    int tid = threadIdx.x;
    __shared__ float Gs[2 * 608];
    for (int idx = tid; idx < 2 * 608; idx += 256) {
        int bb = idx / 608, e = idx % 608;
        float s = 0.f;
        #pragma unroll
        for (int sl = 0; sl < NSLOT; ++sl) s += Gbuf[(bb * NSLOT + sl) * 608 + e];
        Gs[idx] = s;
    }
    __syncthreads();

    int b = tid >> 7, c = tid & 127;
    const float* G = Gs + b * 608;
    const float* sk = G + 576;
    float wr[KS];
    #pragma unroll
    for (int k = 0; k < KS; ++k) wr[k] = W[c * KS + k];
    float s = 0.f;
    #pragma unroll
    for (int k = 0; k < KS; ++k) s = fmaf(wr[k], sk[k], s);
    float s2 = 0.f;
    for (int j = 0; j < KS; ++j) {
        float in = 0.f;
        #pragma unroll
        for (int k = 0; k < KS; ++k) in = fmaf(G[j * KS + k], wr[k], in);
        s2 = fmaf(wr[j], in, s2);
    }
    const float invN = 1.0f / NTOT;
    float mu = s * invN;
    float var = fmaxf(fmaf(-mu, mu, s2 * invN), 0.f);
    float rs = rsqrtf(var + 1e-5f);
    stats[tid * 2] = mu;
    stats[tid * 2 + 1] = rs;

    // passthrough outputs
    for (int i = tid; i < 3072; i += 256) out[i] = clouds[i];
    for (int i = tid; i < 540; i += 256) out[ANCH_OFF + i] = anchors[i];
}

// ---------- K3: feat = relu((W@wts - mu)*rs), LDS transpose, row stores ----------
__launch_bounds__(256)
__global__ void k_out(const float* __restrict__ wts, const float* __restrict__ W,
                      const float* __restrict__ stats, float* __restrict__ out) {
    int bn = blockIdx.x, b = bn >> 9, n = bn & (NC - 1);
    int tid = threadIdx.x, wave = tid >> 6, lane = tid & 63;
    __shared__ float wl[CELLS];
    __shared__ float fl[CO * NA];
    {
        const float4* src = (const float4*)(wts + (size_t)bn * CELLS);
        float4* wl4 = (float4*)wl;
        wl4[tid] = src[tid];
        if (tid < 104) wl4[tid + 256] = src[tid + 256];
    }
    __syncthreads();

    // 2 c x 15 a register tile per thread
    int cpair = tid >> 2, aq = tid & 3;
    int c0 = cpair * 2, a0 = aq * 15;
    float4 w0[6], w1[6];
    {
        const float4* W40 = (const float4*)(W + c0 * KS);
        const float4* W41 = (const float4*)(W + (c0 + 1) * KS);
        #pragma unroll
        for (int j = 0; j < 6; ++j) { w0[j] = W40[j]; w1[j] = W41[j]; }
    }
    float mu0 = stats[(b * CO + c0) * 2],     rs0 = stats[(b * CO + c0) * 2 + 1];
    float mu1 = stats[(b * CO + c0 + 1) * 2], rs1 = stats[(b * CO + c0 + 1) * 2 + 1];
    #pragma unroll
    for (int i = 0; i < 15; ++i) {
        const float4* v4 = (const float4*)(wl + (a0 + i) * KS);
        float s0 = 0.f, s1 = 0.f;
        #pragma unroll
        for (int j = 0; j < 6; ++j) {
            float4 v = v4[j];
            s0 = dot4acc(s0, w0[j], v);
            s1 = dot4acc(s1, w1[j], v);
        }
        fl[c0 * NA + a0 + i]       = fmaxf((s0 - mu0) * rs0, 0.f);
        fl[(c0 + 1) * NA + a0 + i] = fmaxf((s1 - mu1) * rs1, 0.f);
    }
    __syncthreads();

    // coalesced 240B row stores: wave w stores c-rows [w*32, w*32+32)
    #pragma unroll 4
    for (int i = 0; i < 32; ++i) {
        int c = wave * 32 + i;
        if (lane < NA)
            out[FEAT_OFF + (((size_t)(b * CO + c)) * NC + n) * NA + lane] = fl[c * NA + lane];
    }
}

extern "C" void kernel_launch(void* const* d_in, const int* in_sizes, int n_in,
                              void* d_out, int out_size, void* d_ws, size_t ws_size,
                              hipStream_t stream) {
    const float* frag    = (const float*)d_in[0];
    const float* clouds  = (const float*)d_in[1];
    const float* kernels = (const float*)d_in[2];
    const float* W       = (const float*)d_in[3];
    const float* anchors = (const float*)d_in[4];
    float* out = (float*)d_out;

    char* ws = (char*)d_ws;
    float* wts   = (float*)(ws);                        // 1024*1440*4 = 5,898,240 B
    float* Gbuf  = (float*)(ws + 5898240);              // 2*8*608*4  = 38,912 B
    float* stats = (float*)(ws + 5898240 + 38912);      // 256*2*4    = 2,048 B

    hipMemsetAsync(Gbuf, 0, 2 * NSLOT * 608 * sizeof(float), stream);
    k_wts<<<3 * NB * NC, 256, 0, stream>>>(frag, clouds, kernels, wts);
    k_gram<<<NB * NC, 256, 0, stream>>>(wts, Gbuf);
    k_finalize<<<1, 256, 0, stream>>>(Gbuf, W, clouds, anchors, stats, out);
    k_out<<<NB * NC, 256, 0, stream>>>(wts, W, stats, out);
}

// Round 4
// 140.715 us; speedup vs baseline: 1.6966x; 1.1480x over previous
//
#include <hip/hip_runtime.h>
#include <math.h>

#define NC 512
#define NB 2
#define M 1024
#define KS 24
#define NA 60
#define CO 128
#define CELLS 1440
#define CHA 20
#define CCELLS 480
#define NTOT 30720.0f
// log2(e)/SIGMA, SIGMA=0.08
#define LSCALE 18.033688011112043f
#define R2 0.16f
#define NSLOT 32

#define FEAT_OFF 3072
#define ANCH_OFF (3072 + 7864320)

__device__ __forceinline__ float dot4acc(float s, float4 w, float4 v) {
    return fmaf(w.x, v.x, fmaf(w.y, v.y, fmaf(w.z, v.z, fmaf(w.w, v.w, s))));
}

// ---------- K1: wts chunk (20 a's = 480 cells) + fused feature-stats ----------
// grid 3072 = (bn, chunk); accum[b][slot][c][2] gets atomic {sum f, sum f^2}.
__launch_bounds__(256)
__global__ void k_wts(const float* __restrict__ frag, const float* __restrict__ clouds,
                      const float* __restrict__ kernels, const float* __restrict__ W,
                      float* __restrict__ wts, float* __restrict__ accum) {
    int bx = blockIdx.x;
    int chunk = bx % 3;
    int bn = bx / 3;
    int b = bn >> 9, n = bn & (NC - 1);
    int tid = threadIdx.x, wave = tid >> 6, lane = tid & 63;
    __shared__ float4 spl[M];
    __shared__ int wcnt[16];
    __shared__ __align__(16) float swl[512];  // chunk wts (480 used)

    // per-thread cell constants
    int lc0 = tid, lc1 = tid + 256;
    float4 kc0, kc1;
    {
        int cells[2] = {chunk * CCELLS + lc0, chunk * CCELLS + lc1};
        bool vld[2] = {true, lc1 < CCELLS};
        float4* kcs[2] = {&kc0, &kc1};
        #pragma unroll
        for (int q = 0; q < 2; ++q) {
            if (vld[q]) {
                int cell = cells[q];
                int a = cell / KS, k = cell - a * KS;
                const float* kp = kernels + (size_t)(k * NA + a) * 3;
                float kx = kp[0], ky = kp[1], kz = kp[2];
                float k2 = kx * kx + ky * ky + kz * kz;
                *kcs[q] = make_float4(kx * (2.0f * LSCALE), ky * (2.0f * LSCALE),
                                      kz * (2.0f * LSCALE), -k2 * LSCALE);
            } else {
                *kcs[q] = make_float4(0.f, 0.f, 0.f, -1e30f);  // hw exp2 -> 0
            }
        }
    }

    float cx = clouds[b * 3 * NC + n];
    float cy = clouds[b * 3 * NC + NC + n];
    float cz = clouds[b * 3 * NC + 2 * NC + n];

    float dx[4], dy[4], dz[4], ei[4];
    int pos[4];
    bool pr[4];
    unsigned long long lmask = (1ull << lane) - 1ull;
    #pragma unroll
    for (int j = 0; j < 4; ++j) {
        int m = tid + j * 256;
        dx[j] = frag[3 * m]     - cx;
        dy[j] = frag[3 * m + 1] - cy;
        dz[j] = frag[3 * m + 2] - cz;
        // match jnp's non-contracted sum of squares (mask boundary exactness)
        float s = __fmul_rn(dx[j], dx[j]);
        s = __fadd_rn(s, __fmul_rn(dy[j], dy[j]));
        s = __fadd_rn(s, __fmul_rn(dz[j], dz[j]));
        pr[j] = s < R2;
        ei[j] = __builtin_amdgcn_exp2f(-s * LSCALE);
        unsigned long long mk = __ballot(pr[j]);
        pos[j] = __popcll(mk & lmask);
        if (lane == 0) wcnt[j * 4 + wave] = __popcll(mk);
    }
    __syncthreads();
    int run = 0, base[4];
    #pragma unroll
    for (int t2 = 0; t2 < 16; ++t2) {
        if ((t2 & 3) == wave) base[t2 >> 2] = run;
        run += wcnt[t2];
    }
    int cnt = run;
    #pragma unroll
    for (int j = 0; j < 4; ++j)
        if (pr[j]) spl[base[j] + pos[j]] = make_float4(dx[j], dy[j], dz[j], ei[j]);
    __syncthreads();

    float acc0 = 0.f, acc1 = 0.f;
    #pragma unroll 2
    for (int i = 0; i < cnt; ++i) {
        float4 p = spl[i];  // broadcast ds_read_b128; p.w = exp2(-d2*L)
        float a0 = fmaf(p.x, kc0.x, fmaf(p.y, kc0.y, fmaf(p.z, kc0.z, kc0.w)));
        float a1 = fmaf(p.x, kc1.x, fmaf(p.y, kc1.y, fmaf(p.z, kc1.z, kc1.w)));
        acc0 = fmaf(__builtin_amdgcn_exp2f(a0), p.w, acc0);
        acc1 = fmaf(__builtin_amdgcn_exp2f(a1), p.w, acc1);
    }

    float inv = 1.0f / (float)(cnt + 1);
    float w0 = acc0 * inv, w1 = acc1 * inv;
    float* wrow = wts + (size_t)bn * CELLS + chunk * CCELLS;
    wrow[lc0] = w0;
    swl[lc0] = w0;
    if (lc1 < CCELLS) { wrow[lc1] = w1; swl[lc1] = w1; }
    __syncthreads();

    // fused feature stats over this chunk's 20 a's: f = W[c]·v[a], accumulate
    int c = tid >> 1, ah = tid & 1;
    float4 wr[6];
    {
        const float4* W4 = (const float4*)(W + c * KS);
        #pragma unroll
        for (int j = 0; j < 6; ++j) wr[j] = W4[j];
    }
    float fs = 0.f, fs2 = 0.f;
    #pragma unroll
    for (int i = 0; i < 10; ++i) {
        const float4* v4 = (const float4*)(swl + (ah * 10 + i) * KS);
        float f = 0.f;
        #pragma unroll
        for (int j = 0; j < 6; ++j) f = dot4acc(f, wr[j], v4[j]);
        fs += f;
        fs2 = fmaf(f, f, fs2);
    }
    fs  += __shfl_xor(fs, 1);
    fs2 += __shfl_xor(fs2, 1);
    if (ah == 0) {
        int slot = bx & (NSLOT - 1);
        float* ap = accum + (((size_t)(b * NSLOT + slot) * CO + c) * 2);
        atomicAdd(&ap[0], fs);
        atomicAdd(&ap[1], fs2);
    }
}

// ---------- K2: finalize stats per block + feat = relu((f-mu)*rs) ----------
__launch_bounds__(256)
__global__ void k_out(const float* __restrict__ wts, const float* __restrict__ W,
                      const float* __restrict__ accum, const float* __restrict__ clouds,
                      const float* __restrict__ anchors, float* __restrict__ out) {
    int bn = blockIdx.x, b = bn >> 9, n = bn & (NC - 1);
    int tid = threadIdx.x, wave = tid >> 6, lane = tid & 63;
    __shared__ __align__(16) float wl[CELLS];
    __shared__ float fl[CO * NA];
    __shared__ float2 sst[CO];

    // passthrough outputs (first 15 blocks)
    if (bn < 12) {
        int i = bn * 256 + tid;
        out[i] = clouds[i];
    } else if (bn < 15) {
        int i = (bn - 12) * 256 + tid;
        if (i < 540) out[ANCH_OFF + i] = anchors[i];
    }

    // stats: reduce 32 slots per (b,c)
    if (tid < CO) {
        int c = tid;
        float s = 0.f, s2 = 0.f;
        #pragma unroll
        for (int sl = 0; sl < NSLOT; ++sl) {
            const float* ap = accum + (((size_t)(b * NSLOT + sl) * CO + c) * 2);
            s += ap[0];
            s2 += ap[1];
        }
        const float invN = 1.0f / NTOT;
        float mu = s * invN;
        float var = fmaxf(fmaf(-mu, mu, s2 * invN), 0.f);
        sst[c] = make_float2(mu, rsqrtf(var + 1e-5f));
    }
    {
        const float4* src = (const float4*)(wts + (size_t)bn * CELLS);
        float4* wl4 = (float4*)wl;
        wl4[tid] = src[tid];
        if (tid < 104) wl4[tid + 256] = src[tid + 256];
    }
    __syncthreads();

    // 2 c x 15 a register tile per thread
    int cpair = tid >> 2, aq = tid & 3;
    int c0 = cpair * 2, a0 = aq * 15;
    float4 w0[6], w1[6];
    {
        const float4* W40 = (const float4*)(W + c0 * KS);
        const float4* W41 = (const float4*)(W + (c0 + 1) * KS);
        #pragma unroll
        for (int j = 0; j < 6; ++j) { w0[j] = W40[j]; w1[j] = W41[j]; }
    }
    float2 st0 = sst[c0], st1 = sst[c0 + 1];
    #pragma unroll
    for (int i = 0; i < 15; ++i) {
        const float4* v4 = (const float4*)(wl + (a0 + i) * KS);
        float s0 = 0.f, s1 = 0.f;
        #pragma unroll
        for (int j = 0; j < 6; ++j) {
            float4 v = v4[j];
            s0 = dot4acc(s0, w0[j], v);
            s1 = dot4acc(s1, w1[j], v);
        }
        fl[c0 * NA + a0 + i]       = fmaxf((s0 - st0.x) * st0.y, 0.f);
        fl[(c0 + 1) * NA + a0 + i] = fmaxf((s1 - st1.x) * st1.y, 0.f);
    }
    __syncthreads();

    // coalesced 240B row stores: wave w stores c-rows [w*32, w*32+32)
    #pragma unroll 4
    for (int i = 0; i < 32; ++i) {
        int c = wave * 32 + i;
        if (lane < NA)
            out[FEAT_OFF + (((size_t)(b * CO + c)) * NC + n) * NA + lane] = fl[c * NA + lane];
    }
}

extern "C" void kernel_launch(void* const* d_in, const int* in_sizes, int n_in,
                              void* d_out, int out_size, void* d_ws, size_t ws_size,
                              hipStream_t stream) {
    const float* frag    = (const float*)d_in[0];
    const float* clouds  = (const float*)d_in[1];
    const float* kernels = (const float*)d_in[2];
    const float* W       = (const float*)d_in[3];
    const float* anchors = (const float*)d_in[4];
    float* out = (float*)d_out;

    char* ws = (char*)d_ws;
    float* wts   = (float*)(ws);                 // 1024*1440*4 = 5,898,240 B
    float* accum = (float*)(ws + 5898240);       // 2*32*128*2*4 = 65,536 B

    hipMemsetAsync(accum, 0, 2 * NSLOT * CO * 2 * sizeof(float), stream);
    k_wts<<<3 * NB * NC, 256, 0, stream>>>(frag, clouds, kernels, W, wts, accum);
    k_out<<<NB * NC, 256, 0, stream>>>(wts, W, accum, clouds, anchors, out);
}

// Round 6
// 139.637 us; speedup vs baseline: 1.7097x; 1.0077x over previous
//
#include <hip/hip_runtime.h>
#include <math.h>

#define NC 512
#define NB 2
#define M 1024
#define KS 24
#define NA 60
#define CO 128
#define CELLS 1440
#define CCELLS 480
#define NTOT 30720.0f
// log2(e)/SIGMA, SIGMA=0.08
#define LSCALE 18.033688011112043f
#define R2 0.16f
#define NSLOT 32

#define FEAT_OFF 3072
#define ANCH_OFF (3072 + 7864320)

__device__ __forceinline__ float dot4acc(float s, float4 w, float4 v) {
    return fmaf(w.x, v.x, fmaf(w.y, v.y, fmaf(w.z, v.z, fmaf(w.w, v.w, s))));
}

// ---------- K1: wts chunk (20 a's = 480 cells) + fused feature-stats ----------
// grid 3072 = (bn, chunk); accum[b][slot][c][2] gets atomic {sum f, sum f^2}.
__launch_bounds__(256)
__global__ void k_wts(const float* __restrict__ frag, const float* __restrict__ clouds,
                      const float* __restrict__ kernels, const float* __restrict__ W,
                      float* __restrict__ wts, float* __restrict__ accum) {
    int bx = blockIdx.x;
    int chunk = bx % 3;
    int bn = bx / 3;
    int b = bn >> 9, n = bn & (NC - 1);
    int tid = threadIdx.x, wave = tid >> 6, lane = tid & 63;
    __shared__ float4 spl[M];
    __shared__ int wcnt[16];
    __shared__ __align__(16) float swl[512];  // chunk wts (480 used)

    // per-thread cell constants
    int lc0 = tid, lc1 = tid + 256;
    float4 kc0, kc1;
    {
        int cells[2] = {chunk * CCELLS + lc0, chunk * CCELLS + lc1};
        bool vld[2] = {true, lc1 < CCELLS};
        float4* kcs[2] = {&kc0, &kc1};
        #pragma unroll
        for (int q = 0; q < 2; ++q) {
            if (vld[q]) {
                int cell = cells[q];
                int a = cell / KS, k = cell - a * KS;
                const float* kp = kernels + (size_t)(k * NA + a) * 3;
                float kx = kp[0], ky = kp[1], kz = kp[2];
                float k2 = kx * kx + ky * ky + kz * kz;
                *kcs[q] = make_float4(kx * (2.0f * LSCALE), ky * (2.0f * LSCALE),
                                      kz * (2.0f * LSCALE), -k2 * LSCALE);
            } else {
                *kcs[q] = make_float4(0.f, 0.f, 0.f, -1e30f);  // hw exp2 -> 0
            }
        }
    }

    float cx = clouds[b * 3 * NC + n];
    float cy = clouds[b * 3 * NC + NC + n];
    float cz = clouds[b * 3 * NC + 2 * NC + n];

    float dx[4], dy[4], dz[4], ei[4];
    int pos[4];
    bool pr[4];
    unsigned long long lmask = (1ull << lane) - 1ull;
    #pragma unroll
    for (int j = 0; j < 4; ++j) {
        int m = tid + j * 256;
        dx[j] = frag[3 * m]     - cx;
        dy[j] = frag[3 * m + 1] - cy;
        dz[j] = frag[3 * m + 2] - cz;
        // match jnp's non-contracted sum of squares (mask boundary exactness)
        float s = __fmul_rn(dx[j], dx[j]);
        s = __fadd_rn(s, __fmul_rn(dy[j], dy[j]));
        s = __fadd_rn(s, __fmul_rn(dz[j], dz[j]));
        pr[j] = s < R2;
        ei[j] = __builtin_amdgcn_exp2f(-s * LSCALE);
        unsigned long long mk = __ballot(pr[j]);
        pos[j] = __popcll(mk & lmask);
        if (lane == 0) wcnt[j * 4 + wave] = __popcll(mk);
    }
    __syncthreads();
    int run = 0, base[4];
    #pragma unroll
    for (int t2 = 0; t2 < 16; ++t2) {
        if ((t2 & 3) == wave) base[t2 >> 2] = run;
        run += wcnt[t2];
    }
    int cnt = run;
    #pragma unroll
    for (int j = 0; j < 4; ++j)
        if (pr[j]) spl[base[j] + pos[j]] = make_float4(dx[j], dy[j], dz[j], ei[j]);
    __syncthreads();

    // 8 independent dot->exp2->acc chains via unroll-4 over pairs x 2 cells
    float acc0 = 0.f, acc1 = 0.f;
    #pragma unroll 4
    for (int i = 0; i < cnt; ++i) {
        float4 p = spl[i];  // broadcast ds_read_b128; p.w = exp2(-d2*L)
        float a0 = fmaf(p.x, kc0.x, fmaf(p.y, kc0.y, fmaf(p.z, kc0.z, kc0.w)));
        float a1 = fmaf(p.x, kc1.x, fmaf(p.y, kc1.y, fmaf(p.z, kc1.z, kc1.w)));
        acc0 = fmaf(__builtin_amdgcn_exp2f(a0), p.w, acc0);
        acc1 = fmaf(__builtin_amdgcn_exp2f(a1), p.w, acc1);
    }

    float inv = 1.0f / (float)(cnt + 1);
    float w0 = acc0 * inv, w1 = acc1 * inv;
    float* wrow = wts + (size_t)bn * CELLS + chunk * CCELLS;
    wrow[lc0] = w0;
    swl[lc0] = w0;
    if (lc1 < CCELLS) { wrow[lc1] = w1; swl[lc1] = w1; }
    __syncthreads();

    // fused feature stats over this chunk's 20 a's: f = W[c]·v[a], accumulate
    int c = tid >> 1, ah = tid & 1;
    float4 wr[6];
    {
        const float4* W4 = (const float4*)(W + c * KS);
        #pragma unroll
        for (int j = 0; j < 6; ++j) wr[j] = W4[j];
    }
    float fs = 0.f, fs2 = 0.f;
    #pragma unroll
    for (int i = 0; i < 10; ++i) {
        const float4* v4 = (const float4*)(swl + (ah * 10 + i) * KS);
        float f = 0.f;
        #pragma unroll
        for (int j = 0; j < 6; ++j) f = dot4acc(f, wr[j], v4[j]);
        fs += f;
        fs2 = fmaf(f, f, fs2);
    }
    fs  += __shfl_xor(fs, 1);
    fs2 += __shfl_xor(fs2, 1);
    if (ah == 0) {
        int slot = bx & (NSLOT - 1);
        float* ap = accum + (((size_t)(b * NSLOT + slot) * CO + c) * 2);
        atomicAdd(&ap[0], fs);
        atomicAdd(&ap[1], fs2);
    }
}

// ---------- K2: finalize stats (vectorized slot-reduce) + normalized output ----------
__launch_bounds__(256)
__global__ void k_out(const float* __restrict__ wts, const float* __restrict__ W,
                      const float* __restrict__ accum, const float* __restrict__ clouds,
                      const float* __restrict__ anchors, float* __restrict__ out) {
    int bn = blockIdx.x, b = bn >> 9, n = bn & (NC - 1);
    int tid = threadIdx.x, wave = tid >> 6, lane = tid & 63;
    __shared__ __align__(16) float wl[CELLS];
    __shared__ float fl[CO * NA];
    __shared__ float4 sred[256];
    __shared__ float2 sst[CO];

    // vectorized slot-reduce: thread (sg, cp) sums 8 slots of c-pair cp as float4
    // accum float4 view: element (b, slot, cp) at [(b*NSLOT+slot)*64 + cp]
    {
        int cp = tid & 63, sg = tid >> 6;
        const float4* A4 = (const float4*)accum;
        float4 r = make_float4(0.f, 0.f, 0.f, 0.f);
        #pragma unroll
        for (int s = 0; s < 8; ++s) {
            float4 v = A4[((size_t)(b * NSLOT + sg * 8 + s)) * 64 + cp];
            r.x += v.x; r.y += v.y; r.z += v.z; r.w += v.w;
        }
        sred[tid] = r;
    }

    // passthrough outputs (first 15 blocks)
    if (bn < 12) {
        int i = bn * 256 + tid;
        out[i] = clouds[i];
    } else if (bn < 15) {
        int i = (bn - 12) * 256 + tid;
        if (i < 540) out[ANCH_OFF + i] = anchors[i];
    }

    {
        const float4* src = (const float4*)(wts + (size_t)bn * CELLS);
        float4* wl4 = (float4*)wl;
        wl4[tid] = src[tid];
        if (tid < 104) wl4[tid + 256] = src[tid + 256];
    }
    __syncthreads();

    if (tid < 64) {  // cp = tid: finalize stats for c = 2*tid, 2*tid+1
        float4 r0 = sred[tid], r1 = sred[tid + 64], r2 = sred[tid + 128], r3 = sred[tid + 192];
        float s0  = r0.x + r1.x + r2.x + r3.x;
        float q0  = r0.y + r1.y + r2.y + r3.y;
        float s1  = r0.z + r1.z + r2.z + r3.z;
        float q1  = r0.w + r1.w + r2.w + r3.w;
        const float invN = 1.0f / NTOT;
        float mu0 = s0 * invN;
        float var0 = fmaxf(fmaf(-mu0, mu0, q0 * invN), 0.f);
        float mu1 = s1 * invN;
        float var1 = fmaxf(fmaf(-mu1, mu1, q1 * invN), 0.f);
        sst[2 * tid]     = make_float2(mu0, rsqrtf(var0 + 1e-5f));
        sst[2 * tid + 1] = make_float2(mu1, rsqrtf(var1 + 1e-5f));
    }
    __syncthreads();

    // 2 c x 15 a register tile per thread
    int cpair = tid >> 2, aq = tid & 3;
    int c0 = cpair * 2, a0 = aq * 15;
    float4 w0[6], w1[6];
    {
        const float4* W40 = (const float4*)(W + c0 * KS);
        const float4* W41 = (const float4*)(W + (c0 + 1) * KS);
        #pragma unroll
        for (int j = 0; j < 6; ++j) { w0[j] = W40[j]; w1[j] = W41[j]; }
    }
    float2 st0 = sst[c0], st1 = sst[c0 + 1];
    #pragma unroll
    for (int i = 0; i < 15; ++i) {
        const float4* v4 = (const float4*)(wl + (a0 + i) * KS);
        float s0 = 0.f, s1 = 0.f;
        #pragma unroll
        for (int j = 0; j < 6; ++j) {
            float4 v = v4[j];
            s0 = dot4acc(s0, w0[j], v);
            s1 = dot4acc(s1, w1[j], v);
        }
        fl[c0 * NA + a0 + i]       = fmaxf((s0 - st0.x) * st0.y, 0.f);
        fl[(c0 + 1) * NA + a0 + i] = fmaxf((s1 - st1.x) * st1.y, 0.f);
    }
    __syncthreads();

    // coalesced 240B row stores: wave w stores c-rows [w*32, w*32+32)
    #pragma unroll 4
    for (int i = 0; i < 32; ++i) {
        int c = wave * 32 + i;
        if (lane < NA)
            out[FEAT_OFF + (((size_t)(b * CO + c)) * NC + n) * NA + lane] = fl[c * NA + lane];
    }
}

extern "C" void kernel_launch(void* const* d_in, const int* in_sizes, int n_in,
                              void* d_out, int out_size, void* d_ws, size_t ws_size,
                              hipStream_t stream) {
    const float* frag    = (const float*)d_in[0];
    const float* clouds  = (const float*)d_in[1];
    const float* kernels = (const float*)d_in[2];
    const float* W       = (const float*)d_in[3];
    const float* anchors = (const float*)d_in[4];
    float* out = (float*)d_out;

    char* ws = (char*)d_ws;
    float* wts   = (float*)(ws);                 // 1024*1440*4 = 5,898,240 B
    float* accum = (float*)(ws + 5898240);       // 2*32*128*2*4 = 65,536 B

    hipMemsetAsync(accum, 0, 2 * NSLOT * CO * 2 * sizeof(float), stream);
    k_wts<<<3 * NB * NC, 256, 0, stream>>>(frag, clouds, kernels, W, wts, accum);
    k_out<<<NB * NC, 256, 0, stream>>>(wts, W, accum, clouds, anchors, out);
}